// Round 6
// baseline (574.601 us; speedup 1.0000x reference)
//
#include <hip/hip_runtime.h>

// Problem constants
#define F_DIMC 1024
#define HIDC   4096
#define NH     16
#define SEQ    2048
#define BATCH  4
#define ROWS   (BATCH * SEQ)                    // 8192
#define MEG    (1u << 20)
#define QSCALE 0.18033688011112042f             // 0.125 * log2(e)

typedef unsigned short u16t;
typedef __attribute__((ext_vector_type(8))) short short8;   // 8 bf16 (4 VGPRs) — MFMA A/B frag
typedef __attribute__((ext_vector_type(4))) float floatx4;  // MFMA C/D frag
typedef __attribute__((address_space(1))) void gvoid_t;
typedef __attribute__((address_space(3))) void lvoid_t;
#define ASYNC16(g, l) __builtin_amdgcn_global_load_lds((gvoid_t*)(g), (lvoid_t*)(l), 16, 0, 0)

#if __has_builtin(__builtin_amdgcn_exp2f)
#define EXP2(x) __builtin_amdgcn_exp2f(x)       // raw v_exp_f32 (1 trans op)
#else
#define EXP2(x) exp2f(x)
#endif

__device__ __forceinline__ u16t f2bf(float f) {           // RNE float->bf16
    union { float f; unsigned u; } v; v.f = f;
    unsigned r = v.u + 0x7fffu + ((v.u >> 16) & 1u);
    return (u16t)(r >> 16);
}
__device__ __forceinline__ unsigned fasu(float f) {
    union { float f; unsigned u; } v; v.f = f; return v.u;
}

// ---------------------------------------------------------------------------
// LayerNorm: one 256-thread block per row of 1024 floats; bf16 output.
// ---------------------------------------------------------------------------
__global__ __launch_bounds__(256) void ln_kernel(const float* __restrict__ x,
                                                 const float* __restrict__ w,
                                                 const float* __restrict__ b,
                                                 u16t* __restrict__ out) {
    const int row = blockIdx.x;
    const int t = threadIdx.x;
    const float* xp = x + (size_t)row * F_DIMC;

    float4 v = *(const float4*)(xp + t * 4);
    float s  = v.x + v.y + v.z + v.w;
    float ss = v.x * v.x + v.y * v.y + v.z * v.z + v.w * v.w;
    for (int off = 32; off; off >>= 1) {
        s  += __shfl_down(s, off);
        ss += __shfl_down(ss, off);
    }
    __shared__ float red[8];
    const int wid = t >> 6, lid = t & 63;
    if (lid == 0) { red[wid] = s; red[4 + wid] = ss; }
    __syncthreads();
    if (t == 0) {
        float S  = red[0] + red[1] + red[2] + red[3];
        float SS = red[4] + red[5] + red[6] + red[7];
        float mu  = S * (1.0f / F_DIMC);
        float var = SS * (1.0f / F_DIMC) - mu * mu;
        red[0] = mu;
        red[1] = rsqrtf(var + 1e-6f);
    }
    __syncthreads();
    const float mu = red[0], rs = red[1];

    float4 wv = *(const float4*)(w + t * 4);
    float4 bv = *(const float4*)(b + t * 4);
    ushort4 o = make_ushort4(f2bf((v.x - mu) * rs * wv.x + bv.x),
                             f2bf((v.y - mu) * rs * wv.y + bv.y),
                             f2bf((v.z - mu) * rs * wv.z + bv.z),
                             f2bf((v.w - mu) * rs * wv.w + bv.w));
    *(ushort4*)(out + (size_t)row * F_DIMC + t * 4) = o;
}

// ---------------------------------------------------------------------------
// Weight conversion fp32 -> bf16, all 6 matrices in one launch.
// wbuf layout: wq[0,1M) wk[1M,2M) wv[2M,3M) fc[3M,4M) fc1[4M,8M) fc2[8M,12M)
// ---------------------------------------------------------------------------
__global__ __launch_bounds__(256) void wconv_kernel(const float* __restrict__ w0,
        const float* __restrict__ w1, const float* __restrict__ w2,
        const float* __restrict__ w3, const float* __restrict__ w4,
        const float* __restrict__ w5, u16t* __restrict__ dst) {
    const size_t e = ((size_t)blockIdx.x * 256 + threadIdx.x) * 4;
    const float* src; size_t off;
    if      (e < 1 * MEG) { src = w0; off = e; }
    else if (e < 2 * MEG) { src = w1; off = e - 1 * MEG; }
    else if (e < 3 * MEG) { src = w2; off = e - 2 * MEG; }
    else if (e < 4 * MEG) { src = w3; off = e - 3 * MEG; }
    else if (e < 8 * MEG) { src = w4; off = e - 4 * MEG; }
    else                  { src = w5; off = e - 8 * MEG; }
    float4 f = *(const float4*)(src + off);
    *(ushort4*)(dst + e) = make_ushort4(f2bf(f.x), f2bf(f.y), f2bf(f.z), f2bf(f.w));
}

// ---------------------------------------------------------------------------
// Shared GEMM K-loop (m97 structure), 128x128 tile, BK=32, 4 waves 2x2,
// XOR-swizzled LDS, global_load_lds width=16.
// XCD-aware tile swizzle: flat block l -> XCD l%8 owns M-tile rows
// [8*xcd, 8*xcd+8) x all N-tiles, so A-tiles get same-XCD-L2 reuse instead
// of 8 cross-XCD HBM re-fetches. Requires gridDim.y % 8 == 0 (all true).
// Kof/Klen: K-window (for split-K); Kdim is the row stride.
// ---------------------------------------------------------------------------
#define GEMM_PROLOGUE_AND_LOOP(Aq, Wq, Kdim, Kof, Klen)                        \
    __shared__ u16t As[128 * 32] __attribute__((aligned(16)));                 \
    __shared__ u16t Ws[128 * 32] __attribute__((aligned(16)));                 \
    const int t = threadIdx.x;                                                 \
    const int lane = t & 63;                                                   \
    const int wave = t >> 6;                                                   \
    const int wm = wave >> 1, wn = wave & 1;                                   \
    const int l_ = blockIdx.y * gridDim.x + blockIdx.x;                        \
    const int mper_ = gridDim.y >> 3;                                          \
    const int r_ = l_ >> 3;                                                    \
    const int m0 = ((l_ & 7) * mper_ + (r_ % mper_)) * 128;                    \
    const int n0 = (r_ / mper_) * 128;                                         \
    const int b0 = t, b1 = t + 256;                                            \
    const int r0 = b0 >> 2, r1 = b1 >> 2;                                      \
    const int q0_ = (b0 & 3) ^ (r0 & 3) ^ ((r0 >> 2) & 1);                     \
    const int q1_ = (b1 & 3) ^ (r1 & 3) ^ ((r1 >> 2) & 1);                     \
    const u16t* Ag0 = (Aq) + (size_t)(m0 + r0) * (Kdim) + (Kof) + q0_ * 8;     \
    const u16t* Ag1 = (Aq) + (size_t)(m0 + r1) * (Kdim) + (Kof) + q1_ * 8;     \
    const u16t* Wg0 = (Wq) + (size_t)(n0 + r0) * (Kdim) + (Kof) + q0_ * 8;     \
    const u16t* Wg1 = (Wq) + (size_t)(n0 + r1) * (Kdim) + (Kof) + q1_ * 8;     \
    u16t* Al0 = As + b0 * 8;  u16t* Al1 = As + b1 * 8;                         \
    u16t* Wl0 = Ws + b0 * 8;  u16t* Wl1 = Ws + b1 * 8;                         \
    const int fm = lane & 15, fq = lane >> 4;                                  \
    const int swz = fq ^ (fm & 3) ^ ((fm >> 2) & 1);                           \
    const u16t* Afp = As + ((wm * 64 + fm) * 32 + swz * 8);                    \
    const u16t* Wfp = Ws + ((wn * 64 + fm) * 32 + swz * 8);                    \
    floatx4 acc[4][4] = {};                                                    \
    for (int k0 = 0; k0 < (Klen); k0 += 32) {                                  \
        ASYNC16(Ag0, Al0); ASYNC16(Ag1, Al1);                                  \
        ASYNC16(Wg0, Wl0); ASYNC16(Wg1, Wl1);                                  \
        Ag0 += 32; Ag1 += 32; Wg0 += 32; Wg1 += 32;                            \
        __syncthreads();                                                       \
        short8 fa[4], fb[4];                                                   \
        _Pragma("unroll")                                                      \
        for (int i = 0; i < 4; ++i) {                                          \
            fa[i] = *(const short8*)(Afp + i * 16 * 32);                       \
            fb[i] = *(const short8*)(Wfp + i * 16 * 32);                       \
        }                                                                      \
        _Pragma("unroll")                                                      \
        for (int mi = 0; mi < 4; ++mi)                                         \
            _Pragma("unroll")                                                  \
            for (int ni = 0; ni < 4; ++ni)                                     \
                acc[mi][ni] = __builtin_amdgcn_mfma_f32_16x16x32_bf16(         \
                    fa[mi], fb[ni], acc[mi][ni], 0, 0, 0);                     \
        __syncthreads();                                                       \
    }

// ---------------------------------------------------------------------------
// Generic bf16 MFMA GEMM: C = A @ W^T + bias (+ReLU)(+res)
// ---------------------------------------------------------------------------
template <bool RELU, bool RES, bool BF16OUT>
__global__ __launch_bounds__(256) void gemm_mfma(const u16t* __restrict__ A,
                                                 const u16t* __restrict__ W,
                                                 const float* __restrict__ bias,
                                                 const float* res, void* Cout,
                                                 int N, int K) {
    GEMM_PROLOGUE_AND_LOOP(A, W, K, 0, K)
    // Epilogue. C/D layout: col=lane&15, row=(lane>>4)*4+reg  [m89/m91].
    float bl[4];
#pragma unroll
    for (int ni = 0; ni < 4; ++ni) bl[ni] = bias[n0 + wn * 64 + ni * 16 + fm];
#pragma unroll
    for (int mi = 0; mi < 4; ++mi) {
#pragma unroll
        for (int ni = 0; ni < 4; ++ni) {
            const int col = n0 + wn * 64 + ni * 16 + fm;
#pragma unroll
            for (int r = 0; r < 4; ++r) {
                const int row = m0 + wm * 64 + mi * 16 + fq * 4 + r;
                const size_t off = (size_t)row * N + col;
                float c = acc[mi][ni][r] + bl[ni];
                if (RELU) c = fmaxf(c, 0.0f);
                if (RES)  c += res[off];
                if (BF16OUT) ((u16t*)Cout)[off] = f2bf(c);
                else         ((float*)Cout)[off] = c;
            }
        }
    }
}

// ---------------------------------------------------------------------------
// fc2 split-K GEMM: out += ff @ w2^T (+bias on z==0), atomicAdd fp32.
// Grid (8, 64, 2): z = K-half (2048 each) -> 1024 blocks = 4/CU.
// d_out already holds x1 (residual) from step 4.
// ---------------------------------------------------------------------------
__global__ __launch_bounds__(256) void gemm_fc2(const u16t* __restrict__ A,
                                                const u16t* __restrict__ W,
                                                const float* __restrict__ bias,
                                                float* __restrict__ out) {
    const int kz = blockIdx.z;
    GEMM_PROLOGUE_AND_LOOP(A, W, HIDC, kz * (HIDC / 2), HIDC / 2)
    float bl[4];
#pragma unroll
    for (int ni = 0; ni < 4; ++ni)
        bl[ni] = kz == 0 ? bias[n0 + wn * 64 + ni * 16 + fm] : 0.0f;
#pragma unroll
    for (int mi = 0; mi < 4; ++mi)
#pragma unroll
        for (int ni = 0; ni < 4; ++ni) {
            const int col = n0 + wn * 64 + ni * 16 + fm;
#pragma unroll
            for (int r = 0; r < 4; ++r) {
                const int row = m0 + wm * 64 + mi * 16 + fq * 4 + r;
                atomicAdd(out + (size_t)row * F_DIMC + col, acc[mi][ni][r] + bl[ni]);
            }
        }
}

// ---------------------------------------------------------------------------
// Fused QKV GEMM: A = h [8192][1024], W = W_qkv [3072][1024].
// Epilogue routes per col-block (block-uniform): q (scaled by QSCALE) -> qb,
// k -> kb, v -> vtb TRANSPOSED (vtb[d][token], packed 4-row ushort4 stores).
// ---------------------------------------------------------------------------
__global__ __launch_bounds__(256) void gemm_qkv(const u16t* __restrict__ A,
        const u16t* __restrict__ W,
        const float* __restrict__ wq_b, const float* __restrict__ wk_b,
        const float* __restrict__ wv_b,
        u16t* __restrict__ qb, u16t* __restrict__ kb, u16t* __restrict__ vtb) {
    GEMM_PROLOGUE_AND_LOOP(A, W, F_DIMC, 0, F_DIMC)
    const int which = n0 >> 10;                 // 0=q 1=k 2=v (n0 mult of 128)
    const int nb = n0 & 1023;
    const float* bias = which == 0 ? wq_b : which == 1 ? wk_b : wv_b;
    float bl[4];
#pragma unroll
    for (int ni = 0; ni < 4; ++ni) bl[ni] = bias[nb + wn * 64 + ni * 16 + fm];

    if (which == 2) {
        // v: transposed store, 4 consecutive tokens packed per ushort4
#pragma unroll
        for (int mi = 0; mi < 4; ++mi)
#pragma unroll
            for (int ni = 0; ni < 4; ++ni) {
                const int col = nb + wn * 64 + ni * 16 + fm;       // d index
                const int row0 = m0 + wm * 64 + mi * 16 + fq * 4;  // token
                ushort4 pk = make_ushort4(f2bf(acc[mi][ni][0] + bl[ni]),
                                          f2bf(acc[mi][ni][1] + bl[ni]),
                                          f2bf(acc[mi][ni][2] + bl[ni]),
                                          f2bf(acc[mi][ni][3] + bl[ni]));
                *(ushort4*)(vtb + (size_t)col * ROWS + row0) = pk;
            }
    } else {
        u16t* dst = (which == 0) ? qb : kb;
        const float sc = (which == 0) ? QSCALE : 1.0f;
#pragma unroll
        for (int mi = 0; mi < 4; ++mi)
#pragma unroll
            for (int ni = 0; ni < 4; ++ni) {
                const int col = nb + wn * 64 + ni * 16 + fm;
#pragma unroll
                for (int r = 0; r < 4; ++r) {
                    const int row = m0 + wm * 64 + mi * 16 + fq * 4 + r;
                    dst[(size_t)row * F_DIMC + col] = f2bf((acc[mi][ni][r] + bl[ni]) * sc);
                }
            }
    }
}

// ---------------------------------------------------------------------------
// MFMA flash attention, v3 (unchanged from round 5):
//  raw v_exp_f32; truncating v_perm P-pack; l via ones-MFMA; 40 KB LDS
//  (K double-buffered, V single) -> 4 blocks/CU.
// ---------------------------------------------------------------------------
__global__ __launch_bounds__(256, 4) void attn_mfma(const u16t* __restrict__ qb,
        const u16t* __restrict__ kbuf, const u16t* __restrict__ vtb,
        u16t* __restrict__ ab) {
    __shared__ u16t Kt[2][64 * 64] __attribute__((aligned(16)));   // 16 KB
    __shared__ u16t Vs[64 * 64] __attribute__((aligned(16)));      // 8 KB
    __shared__ u16t QP[128 * 64] __attribute__((aligned(16)));     // 16 KB

    const int t = threadIdx.x;
    const int lane = t & 63;
    const int wave = t >> 6;
    const int l15 = lane & 15, q4 = lane >> 4;
    const int q0 = blockIdx.x * 128;
    const int bh = blockIdx.y;
    const int b = bh >> 4, hh = bh & 15;

    // ---- stage Q (cooperative): 1024 16B-blocks, swizzled ----
#pragma unroll
    for (int c = 0; c < 4; ++c) {
        const int beta = c * 256 + t;
        const int r = beta >> 3, o = (beta & 7) ^ (r & 7);
        ASYNC16(qb + (size_t)(b * SEQ + q0 + r) * F_DIMC + hh * 64 + o * 8,
                QP + beta * 8);
    }
    const u16t* kg = kbuf + (size_t)(b * SEQ) * F_DIMC + hh * 64;
    const u16t* vg = vtb + (size_t)(hh * 64) * ROWS + b * SEQ;

    // per-thread staging coords (loop-invariant)
    const int sb0 = t, sb1 = t + 256;
    const int sr0 = sb0 >> 3, so0 = (sb0 & 7) ^ (sr0 & 7);
    const int sr1 = sb1 >> 3, so1 = (sb1 & 7) ^ (sr1 & 7);
    const u16t* kp0 = kg + (size_t)sr0 * F_DIMC + so0 * 8;
    const u16t* kp1 = kg + (size_t)sr1 * F_DIMC + so1 * 8;
    const u16t* vp0 = vg + (size_t)sr0 * ROWS + so0 * 8;
    const u16t* vp1 = vg + (size_t)sr1 * ROWS + so1 * 8;

    // ---- pre-stage K0 -> Kt[0], V0 -> Vs ----
    ASYNC16(kp0, Kt[0] + sb0 * 8);
    ASYNC16(kp1, Kt[0] + sb1 * 8);
    ASYNC16(vp0, Vs + sb0 * 8);
    ASYNC16(vp1, Vs + sb1 * 8);
    kp0 += 64 * F_DIMC; kp1 += 64 * F_DIMC; vp0 += 64; vp1 += 64;
    __syncthreads();                       // Q + tile0 resident

    // ---- Q B-frags (this wave's 32 rows) ----
    short8 fqr[2][2];
#pragma unroll
    for (int mt = 0; mt < 2; ++mt)
#pragma unroll
        for (int ks = 0; ks < 2; ++ks) {
            const int m = wave * 32 + mt * 16 + l15;
            const int oct = ks * 4 + q4;
            fqr[mt][ks] = *(const short8*)(QP + (m * 8 + (oct ^ (m & 7))) * 8);
        }
    // From here QP rows [wave*32, wave*32+32) are private to this wave (P).

    short8 ones;                           // bf16 1.0 broadcast (B operand)
#pragma unroll
    for (int i = 0; i < 8; ++i) ones[i] = (short)0x3F80;

    floatx4 oacc[2][4] = {};
    floatx4 lacc[2] = {};

    for (int it = 0; it < SEQ / 64; ++it) {
        // prefetch K(it+1) into the other K buffer
        if (it + 1 < SEQ / 64) {
            u16t* kd = Kt[(it + 1) & 1];
            ASYNC16(kp0, kd + sb0 * 8);
            ASYNC16(kp1, kd + sb1 * 8);
            kp0 += 64 * F_DIMC; kp1 += 64 * F_DIMC;
        }
        const u16t* kcur = Kt[it & 1];

        // ---- S^T = K @ Q^T : C rows = keys, cols = queries ----
        short8 fk[4][2];
#pragma unroll
        for (int nt = 0; nt < 4; ++nt)
#pragma unroll
            for (int ks = 0; ks < 2; ++ks) {
                const int kr = nt * 16 + l15;
                const int oct = ks * 4 + q4;
                fk[nt][ks] = *(const short8*)(kcur + (kr * 8 + (oct ^ (kr & 7))) * 8);
            }
        floatx4 st[2][4] = {};
#pragma unroll
        for (int mt = 0; mt < 2; ++mt)
#pragma unroll
            for (int nt = 0; nt < 4; ++nt) {
                st[mt][nt] = __builtin_amdgcn_mfma_f32_16x16x32_bf16(
                    fk[nt][0], fqr[mt][0], st[mt][nt], 0, 0, 0);
                st[mt][nt] = __builtin_amdgcn_mfma_f32_16x16x32_bf16(
                    fk[nt][1], fqr[mt][1], st[mt][nt], 0, 0, 0);
            }

        // ---- P = exp2(S^T), truncate-pack via v_perm, b64 writes (own rows)
#pragma unroll
        for (int mt = 0; mt < 2; ++mt)
#pragma unroll
            for (int nt = 0; nt < 4; ++nt) {
                const float p0 = EXP2(st[mt][nt][0]);
                const float p1 = EXP2(st[mt][nt][1]);
                const float p2 = EXP2(st[mt][nt][2]);
                const float p3 = EXP2(st[mt][nt][3]);
                const unsigned lo = __builtin_amdgcn_perm(fasu(p1), fasu(p0), 0x07060302u);
                const unsigned hi = __builtin_amdgcn_perm(fasu(p3), fasu(p2), 0x07060302u);
                const int m = wave * 32 + mt * 16 + l15;
                const int logb = nt * 2 + (q4 >> 1);       // 16B-block of k0
                *(uint2*)(QP + (m * 8 + (logb ^ (m & 7))) * 8 + (q4 & 1) * 4) =
                    make_uint2(lo, hi);
            }

        __syncthreads();   // B: drains V(it) (issued last iter) + K(it+1)

        // ---- O += P @ V ;  l += P @ 1 ----
        short8 fp[2][2], fv[4][2];
#pragma unroll
        for (int mt = 0; mt < 2; ++mt)
#pragma unroll
            for (int ks = 0; ks < 2; ++ks) {
                const int m = wave * 32 + mt * 16 + l15;
                const int oct = ks * 4 + q4;
                fp[mt][ks] = *(const short8*)(QP + (m * 8 + (oct ^ (m & 7))) * 8);
            }
#pragma unroll
        for (int nd = 0; nd < 4; ++nd)
#pragma unroll
            for (int ks = 0; ks < 2; ++ks) {
                const int d = nd * 16 + l15;
                const int oct = ks * 4 + q4;
                fv[nd][ks] = *(const short8*)(Vs + (d * 8 + (oct ^ (d & 7))) * 8);
            }
#pragma unroll
        for (int mt = 0; mt < 2; ++mt) {
#pragma unroll
            for (int nd = 0; nd < 4; ++nd) {
                oacc[mt][nd] = __builtin_amdgcn_mfma_f32_16x16x32_bf16(
                    fp[mt][0], fv[nd][0], oacc[mt][nd], 0, 0, 0);
                oacc[mt][nd] = __builtin_amdgcn_mfma_f32_16x16x32_bf16(
                    fp[mt][1], fv[nd][1], oacc[mt][nd], 0, 0, 0);
            }
            lacc[mt] = __builtin_amdgcn_mfma_f32_16x16x32_bf16(
                fp[mt][0], ones, lacc[mt], 0, 0, 0);
            lacc[mt] = __builtin_amdgcn_mfma_f32_16x16x32_bf16(
                fp[mt][1], ones, lacc[mt], 0, 0, 0);
        }

        __syncthreads();   // A: all waves done reading Vs
        if (it + 1 < SEQ / 64) {           // V(it+1) into Vs, in flight until B
            ASYNC16(vp0, Vs + sb0 * 8);
            ASYNC16(vp1, Vs + sb1 * 8);
            vp0 += 64; vp1 += 64;
        }
    }

    // ---- epilogue: lacc rows match oacc rows exactly; no shuffles ----
#pragma unroll
    for (int mt = 0; mt < 2; ++mt) {
        floatx4 rinv;
#pragma unroll
        for (int r = 0; r < 4; ++r) rinv[r] = 1.0f / lacc[mt][r];
#pragma unroll
        for (int nd = 0; nd < 4; ++nd)
#pragma unroll
            for (int r = 0; r < 4; ++r) {
                const int row = b * SEQ + q0 + wave * 32 + mt * 16 + q4 * 4 + r;
                const int col = hh * 64 + nd * 16 + l15;
                ab[(size_t)row * F_DIMC + col] = f2bf(oacc[mt][nd][r] * rinv[r]);
            }
    }
}

// ---------------------------------------------------------------------------
// Launcher. Workspace (u16 units, 52M u16 = 104 MB):
//   wbuf [0,12M) | h [12M,20M) | qb [20M,28M) | kb [28M,36M) | vtb [36M,44M)
//   ab [44M,52M) | ff overlays qb..vtb (32M) after attention consumed.
// ---------------------------------------------------------------------------
extern "C" void kernel_launch(void* const* d_in, const int* in_sizes, int n_in,
                              void* d_out, int out_size, void* d_ws, size_t ws_size,
                              hipStream_t stream) {
    const float* x     = (const float*)d_in[0];
    const float* ln1_w = (const float*)d_in[1];
    const float* ln1_b = (const float*)d_in[2];
    const float* wq_w  = (const float*)d_in[3];
    const float* wq_b  = (const float*)d_in[4];
    const float* wk_w  = (const float*)d_in[5];
    const float* wk_b  = (const float*)d_in[6];
    const float* wv_w  = (const float*)d_in[7];
    const float* wv_b  = (const float*)d_in[8];
    const float* fc_w  = (const float*)d_in[9];
    const float* fc_b  = (const float*)d_in[10];
    const float* ln2_w = (const float*)d_in[11];
    const float* ln2_b = (const float*)d_in[12];
    const float* fc1_w = (const float*)d_in[13];
    const float* fc1_b = (const float*)d_in[14];
    const float* fc2_w = (const float*)d_in[15];
    const float* fc2_b = (const float*)d_in[16];

    float* out = (float*)d_out;
    u16t*  ws  = (u16t*)d_ws;

    u16t* wbuf = ws;
    u16t* bwqkv = wbuf;                 // [3072][1024] fused
    u16t* bwfc = wbuf + 3 * MEG;
    u16t* bwf1 = wbuf + 4 * MEG;
    u16t* bwf2 = wbuf + 8 * MEG;
    u16t* h    = wbuf + 12 * MEG;
    u16t* qb   = h + 8 * MEG;
    u16t* kb   = qb + 8 * MEG;
    u16t* vtb  = kb + 8 * MEG;
    u16t* ab   = vtb + 8 * MEG;
    u16t* ff   = qb;                    // overlay: qb/kb/vtb dead by step 6

    const dim3 blk(256);
    const dim3 gF(F_DIMC / 128, ROWS / 128);      // (8, 64)
    const dim3 gQKV(3072 / 128, ROWS / 128);      // (24, 64)
    const dim3 gH(HIDC / 128, ROWS / 128);        // (32, 64)
    const dim3 gF2(F_DIMC / 128, ROWS / 128, 2);  // (8, 64, 2) split-K

    // 0. weights -> bf16
    wconv_kernel<<<12 * MEG / 1024, blk, 0, stream>>>(wq_w, wk_w, wv_w, fc_w, fc1_w, fc2_w, wbuf);
    // 1. h = LN1(x)
    ln_kernel<<<ROWS, blk, 0, stream>>>(x, ln1_w, ln1_b, h);
    // 2. fused q (scaled), k, v^T
    gemm_qkv<<<gQKV, blk, 0, stream>>>(h, bwqkv, wq_b, wk_b, wv_b, qb, kb, vtb);
    // 3. attention (MFMA flash v3)
    attn_mfma<<<dim3(SEQ / 128, BATCH * NH), blk, 0, stream>>>(qb, kb, vtb, ab);
    // 4. x1 = x + attn @ fc_w.T + fc_b  (fp32, into d_out)
    gemm_mfma<false, true, false><<<gF, blk, 0, stream>>>(ab, bwfc, fc_b, x, out, F_DIMC, F_DIMC);
    // 5. h = LN2(x1)
    ln_kernel<<<ROWS, blk, 0, stream>>>(out, ln2_w, ln2_b, h);
    // 6. ff = relu(h @ fc1_w.T + fc1_b)
    gemm_mfma<true, false, true><<<gH, blk, 0, stream>>>(h, bwf1, fc1_b, nullptr, ff, HIDC, F_DIMC);
    // 7. out += ff @ fc2_w.T + fc2_b   (split-K=2, atomic fp32; out holds x1)
    gemm_fc2<<<gF2, blk, 0, stream>>>(ff, bwf2, fc2_b, out);
}